// Round 7
// baseline (549.781 us; speedup 1.0000x reference)
//
#include <hip/hip_runtime.h>
#include <hip/hip_bf16.h>
#include <math.h>

typedef __bf16 bf16;
typedef __bf16 bf16x4 __attribute__((ext_vector_type(4)));
typedef __bf16 bf16x8 __attribute__((ext_vector_type(8)));
typedef float f32x4 __attribute__((ext_vector_type(4)));

#define DEV static __device__ __forceinline__

constexpr int Dm = 1024;   // model dim
constexpr int Sq = 2048;   // seq len
constexpr int Mrows = 4096; // B*S
constexpr size_t AE = (size_t)Mrows * Dm; // elems per activation array

DEV void gload_lds16(const void* g, void* l) {
  __builtin_amdgcn_global_load_lds((const __attribute__((address_space(1))) unsigned int*)g,
                                   (__attribute__((address_space(3))) unsigned int*)l,
                                   16, 0, 0);
}

DEV float gelu_f(float u) {
  const float c = 0.7978845608028654f; // sqrt(2/pi)
  float t = c * (u + 0.044715f * u * u * u);
  // 0.5*(1+tanh(t)) == sigmoid(2t)
  return u / (1.0f + __expf(-2.0f * t));
}

// ---------------- fused transpose of the four 1024x1024 weights ----------------
__global__ void transpose_qkvo_kernel(const float* __restrict__ Wq, const float* __restrict__ Wk,
                                      const float* __restrict__ Wv, const float* __restrict__ Wo,
                                      bf16* __restrict__ Tqkv, bf16* __restrict__ To) {
  const int z = blockIdx.z;
  const float* W = (z == 0) ? Wq : (z == 1) ? Wk : (z == 2) ? Wv : Wo;
  bf16* T = (z < 3) ? (Tqkv + (size_t)z * 1024 * 1024) : To;
  __shared__ float tile[64][65];
  const int t = threadIdx.x;
  const int nt = blockIdx.x * 64, kt = blockIdx.y * 64;
  #pragma unroll
  for (int i = 0; i < 16; ++i) {
    int id = i * 256 + t;
    int r = id >> 6, c = id & 63;
    tile[r][c] = W[(size_t)(kt + r) * 1024 + nt + c];
  }
  __syncthreads();
  #pragma unroll
  for (int i = 0; i < 16; ++i) {
    int id = i * 256 + t;
    int n = id >> 6, k = id & 63;
    T[(size_t)(nt + n) * 1024 + kt + k] = (bf16)tile[k][n];
  }
}

// ---------------- weight transpose: W[K][N] -> T[N][K] (bf16) ----------------
__global__ void transpose_split_kernel(const float* __restrict__ W,
                                       bf16* __restrict__ Thi,
                                       int K, int N) {
  __shared__ float tile[64][65];
  const int t = threadIdx.x;
  const int nt = blockIdx.x * 64, kt = blockIdx.y * 64;
  #pragma unroll
  for (int i = 0; i < 16; ++i) {
    int id = i * 256 + t;
    int r = id >> 6, c = id & 63;
    tile[r][c] = W[(size_t)(kt + r) * N + nt + c];
  }
  __syncthreads();
  #pragma unroll
  for (int i = 0; i < 16; ++i) {
    int id = i * 256 + t;
    int n = id >> 6, k = id & 63;
    Thi[(size_t)(nt + n) * K + kt + k] = (bf16)tile[k][n];
  }
}

// ---------------- LayerNorm -> bf16 (one block per row of 1024) ----------------
__global__ void ln_kernel(const float* __restrict__ x,
                          const float* __restrict__ gamma, const float* __restrict__ beta,
                          bf16* __restrict__ ohi) {
  const int row = blockIdx.x, t = threadIdx.x;
  const float4 v = ((const float4*)(x + (size_t)row * Dm))[t];
  float s = v.x + v.y + v.z + v.w;
  float sq = v.x * v.x + v.y * v.y + v.z * v.z + v.w * v.w;
  #pragma unroll
  for (int off = 1; off < 64; off <<= 1) {
    s += __shfl_xor(s, off);
    sq += __shfl_xor(sq, off);
  }
  __shared__ float red[8];
  const int wave = t >> 6, lane = t & 63;
  if (lane == 0) { red[wave] = s; red[4 + wave] = sq; }
  __syncthreads();
  s = red[0] + red[1] + red[2] + red[3];
  sq = red[4] + red[5] + red[6] + red[7];
  const float mean = s * (1.0f / 1024.0f);
  const float var = sq * (1.0f / 1024.0f) - mean * mean;
  const float inv = 1.0f / sqrtf(var + 1e-5f);
  const float4 g4 = ((const float4*)gamma)[t];
  const float4 b4 = ((const float4*)beta)[t];
  bf16x4 hv;
  hv[0] = (bf16)((v.x - mean) * inv * g4.x + b4.x);
  hv[1] = (bf16)((v.y - mean) * inv * g4.y + b4.y);
  hv[2] = (bf16)((v.z - mean) * inv * g4.z + b4.z);
  hv[3] = (bf16)((v.w - mean) * inv * g4.w + b4.w);
  ((bf16x4*)(ohi + (size_t)row * Dm))[t] = hv;
}

// ---------------- bf16 GEMM: C = A @ B^T(stored [N][K]) ----------------
// kt-outer, single pass. Tile 64x128, 4 waves (2x2), 24KB LDS -> 6 blocks/CU.
// XCD-swizzled block ids. EP: 0 = QKV epilogue, 1 = bias+residual fp32, 2 = gelu.
template<int EP>
__global__ __launch_bounds__(256, 6) void gemm_kernel(
    const bf16* __restrict__ Ahi,
    const bf16* __restrict__ Bthi,
    int K, int N,
    bf16* __restrict__ Ohi,
    float* __restrict__ Of,
    const float* __restrict__ bias, const float* __restrict__ resid) {
  const int t = threadIdx.x, wave = t >> 6, lane = t & 63;
  const int wr = wave >> 1, wc = wave & 1;
  const int l15 = lane & 15, l4 = lane >> 4;
  // bijective XCD swizzle (nwg % 8 == 0 for all launches)
  const int nwg = gridDim.x * gridDim.y;
  const int p0 = blockIdx.y * gridDim.x + blockIdx.x;
  const int swz = (p0 & 7) * (nwg >> 3) + (p0 >> 3);
  const int row0 = (swz / gridDim.x) * 64, col0 = (swz % gridDim.x) * 128;

  __shared__ __align__(16) bf16 sAh[64 * 64];
  __shared__ __align__(16) bf16 sBh[128 * 64];

  f32x4 acc[2][4];
  #pragma unroll
  for (int m = 0; m < 2; ++m)
    #pragma unroll
    for (int n = 0; n < 4; ++n)
      acc[m][n] = (f32x4){0.f, 0.f, 0.f, 0.f};

  for (int kt = 0; kt < K; kt += 64) {
    // stage A [64][64] and B [128][64]; global chunk pre-swizzled, LDS linear
    #pragma unroll
    for (int p = 0; p < 2; ++p) {
      int id = p * 256 + t;
      int r = id >> 3, c = id & 7;
      int cs = (c ^ (r & 7)) << 3;
      gload_lds16(Ahi + (size_t)(row0 + r) * K + kt + cs,
                  (char*)sAh + (p * 256 + wave * 64) * 16);
    }
    #pragma unroll
    for (int p = 0; p < 4; ++p) {
      int id = p * 256 + t;
      int r = id >> 3, c = id & 7;
      int cs = (c ^ (r & 7)) << 3;
      gload_lds16(Bthi + (size_t)(col0 + r) * K + kt + cs,
                  (char*)sBh + (p * 256 + wave * 64) * 16);
    }
    __syncthreads();

    bf16x8 afh[2][2], bfh[4][2];
    #pragma unroll
    for (int m = 0; m < 2; ++m)
      #pragma unroll
      for (int ks = 0; ks < 2; ++ks) {
        int r = wr * 32 + m * 16 + l15;
        int ch = ((ks * 4 + l4) ^ (r & 7)) << 3;
        afh[m][ks] = *(const bf16x8*)&sAh[r * 64 + ch];
      }
    #pragma unroll
    for (int n = 0; n < 4; ++n)
      #pragma unroll
      for (int ks = 0; ks < 2; ++ks) {
        int r = wc * 64 + n * 16 + l15;
        int ch = ((ks * 4 + l4) ^ (r & 7)) << 3;
        bfh[n][ks] = *(const bf16x8*)&sBh[r * 64 + ch];
      }
    #pragma unroll
    for (int ks = 0; ks < 2; ++ks)
      #pragma unroll
      for (int m = 0; m < 2; ++m)
        #pragma unroll
        for (int n = 0; n < 4; ++n)
          acc[m][n] = __builtin_amdgcn_mfma_f32_16x16x32_bf16(afh[m][ks], bfh[n][ks], acc[m][n], 0, 0, 0);
    __syncthreads();
  }

  // epilogue
  #pragma unroll
  for (int m = 0; m < 2; ++m)
    #pragma unroll
    for (int n = 0; n < 4; ++n)
      #pragma unroll
      for (int rr = 0; rr < 4; ++rr) {
        int row = row0 + wr * 32 + m * 16 + l4 * 4 + rr;
        int col = col0 + wc * 64 + n * 16 + l15;
        float v = acc[m][n][rr];
        if constexpr (EP == 0) {
          int which = col >> 10;
          int c = col & 1023;
          if (which == 0) {
            float q = v * 0.18033688011111793f;  // 0.125 * log2(e) pre-folded into Q
            bf16 hi = (bf16)q;
            size_t ad = (size_t)row * Dm + c;
            Ohi[ad] = hi; Ohi[AE + ad] = (bf16)(q - (float)hi);  // q hi/lo
          } else if (which == 1) {
            size_t ad = (size_t)row * Dm + c;
            Ohi[2 * AE + ad] = (bf16)v;                          // k
          } else {
            size_t ad = ((size_t)(row >> 11) * Dm + c) * Sq + (row & (Sq - 1));
            Ohi[4 * AE + ad] = (bf16)v;                          // v transposed [b][h*64+hd][s]
          }
        } else if constexpr (EP == 1) {
          size_t ad = (size_t)row * N + col;
          Of[ad] = v + bias[col] + resid[ad];
        } else {
          size_t ad = (size_t)row * N + col;
          Ohi[ad] = (bf16)gelu_f(v + bias[col]);
        }
      }
}

// ---------------- causal flash attention, single-buffered K/V, 6 blocks/CU ----------------
// grid: 1024 blocks, one 64-row q-tile each; 4 waves x 16 q-rows.
// LPT schedule: heaviest q-tiles dispatched first (qt = 31 - qidx), tail backfills with
// cost-1 blocks under ANY dispatcher. i&7 spreads XCDs; 4 heads per XCD keep K/V L2-resident.
__global__ __launch_bounds__(256, 6) void attn_kernel(
    const bf16* __restrict__ qhi, const bf16* __restrict__ qlo,
    const bf16* __restrict__ khi, const bf16* __restrict__ vthi,
    bf16* __restrict__ chi) {
  const int t = threadIdx.x, wave = t >> 6, lane = t & 63;
  const int l15 = lane & 15, l4 = lane >> 4;
  const int i = blockIdx.x;
  const int xcd = i & 7, j = i >> 3;   // j in [0,128) within XCD
  const int hl = j & 3, qidx = j >> 2; // 4 heads/XCD, qidx in [0,32)
  const int qt = 31 - qidx;            // descending cost (LPT)
  const int bh = xcd * 4 + hl;
  const int b = bh >> 4, h = bh & 15;
  const int qb = qt * 64;
  const int q0 = qb + wave * 16;

  __shared__ __align__(16) bf16 sK[4096], sV[4096], sP[4096];  // 24 KB

  // hoist Q fragments (hi and lo); Q is pre-scaled by 0.125*log2e
  bf16x8 qfh[2], qfl[2];
  #pragma unroll
  for (int ks = 0; ks < 2; ++ks) {
    size_t ad = (size_t)(b * Sq + q0 + l15) * Dm + h * 64 + ks * 32 + l4 * 8;
    qfh[ks] = *(const bf16x8*)&qhi[ad];
    qfl[ks] = *(const bf16x8*)&qlo[ad];
  }

  f32x4 cacc[4];
  float mrun[4], lrun[4];
  #pragma unroll
  for (int nd = 0; nd < 4; ++nd) cacc[nd] = (f32x4){0.f, 0.f, 0.f, 0.f};
  #pragma unroll
  for (int rr = 0; rr < 4; ++rr) { mrun[rr] = -3e38f; lrun[rr] = 0.f; }

  for (int kb = 0; kb <= qb; kb += 64) {
    // stage K [64 s][64 d] and V^T [64 d][64 s] (single buffer; cross-block TLP hides drain)
    #pragma unroll
    for (int p = 0; p < 2; ++p) {
      int id = p * 256 + t;
      int r = id >> 3, c = id & 7;
      int cc = (c ^ (r & 7)) << 3;
      size_t ka = (size_t)(b * Sq + kb + r) * Dm + h * 64 + cc;
      size_t va = (size_t)(b * Dm + h * 64 + r) * Sq + kb + cc;
      gload_lds16(&khi[ka], (char*)sK + (p * 256 + wave * 64) * 16);
      gload_lds16(&vthi[va], (char*)sV + (p * 256 + wave * 64) * 16);
    }
    __syncthreads();   // drains vmcnt (gload_lds) for all waves

    // ---------- S = Q K^T (q_hi + q_lo passes) ----------
    f32x4 sacc[4];
    #pragma unroll
    for (int nk = 0; nk < 4; ++nk) sacc[nk] = (f32x4){0.f, 0.f, 0.f, 0.f};
    {
      bf16x8 kf[4][2];
      #pragma unroll
      for (int nk = 0; nk < 4; ++nk)
        #pragma unroll
        for (int ks = 0; ks < 2; ++ks) {
          int r = nk * 16 + l15;
          int ch = ((ks * 4 + l4) ^ (r & 7)) << 3;
          kf[nk][ks] = *(const bf16x8*)&sK[r * 64 + ch];
        }
      __builtin_amdgcn_s_setprio(1);
      #pragma unroll
      for (int ks = 0; ks < 2; ++ks)
        #pragma unroll
        for (int nk = 0; nk < 4; ++nk)
          sacc[nk] = __builtin_amdgcn_mfma_f32_16x16x32_bf16(qfh[ks], kf[nk][ks], sacc[nk], 0, 0, 0);
      #pragma unroll
      for (int ks = 0; ks < 2; ++ks)
        #pragma unroll
        for (int nk = 0; nk < 4; ++nk)
          sacc[nk] = __builtin_amdgcn_mfma_f32_16x16x32_bf16(qfl[ks], kf[nk][ks], sacc[nk], 0, 0, 0);
      __builtin_amdgcn_s_setprio(0);
    }

    // ---------- causal mask (diagonal block only), online softmax in log2 domain ----------
    const bool diag = (kb == qb);
    #pragma unroll
    for (int rr = 0; rr < 4; ++rr) {
      float mx = -3e38f;
      #pragma unroll
      for (int nk = 0; nk < 4; ++nk) {
        float tv = sacc[nk][rr];
        if (diag && (nk * 16 + l15 > wave * 16 + l4 * 4 + rr)) tv = -3e38f;
        sacc[nk][rr] = tv;
        mx = fmaxf(mx, tv);
      }
      mx = fmaxf(mx, __shfl_xor(mx, 1));
      mx = fmaxf(mx, __shfl_xor(mx, 2));
      mx = fmaxf(mx, __shfl_xor(mx, 4));
      mx = fmaxf(mx, __shfl_xor(mx, 8));
      float mold = mrun[rr];
      if (mx > mold + 8.0f) {        // defer-max: only rescale on big jumps
        float corr = exp2f(mold - mx);
        lrun[rr] *= corr;
        #pragma unroll
        for (int nd = 0; nd < 4; ++nd) cacc[nd][rr] *= corr;
        mrun[rr] = mx;
        mold = mx;
      }
      float rs = 0.f;
      #pragma unroll
      for (int nk = 0; nk < 4; ++nk) {
        float p = exp2f(sacc[nk][rr] - mold);
        sacc[nk][rr] = p;
        rs += p;
      }
      rs += __shfl_xor(rs, 1);
      rs += __shfl_xor(rs, 2);
      rs += __shfl_xor(rs, 4);
      rs += __shfl_xor(rs, 8);
      lrun[rr] += rs;
    }

    // ---------- write P (bf16) to swizzled LDS (wave-private rows; no barrier needed) ----------
    #pragma unroll
    for (int nk = 0; nk < 4; ++nk)
      #pragma unroll
      for (int rr = 0; rr < 4; ++rr) {
        int row = wave * 16 + l4 * 4 + rr;
        int col = nk * 16 + l15;
        int ad = row * 64 + (((col >> 3) ^ (row & 7)) << 3) + (col & 7);
        sP[ad] = (bf16)sacc[nk][rr];
      }

    // ---------- ctx += P V ----------
    {
      bf16x8 pf[2];
      #pragma unroll
      for (int ks = 0; ks < 2; ++ks) {
        int r = wave * 16 + l15;
        int ch = ((ks * 4 + l4) ^ (r & 7)) << 3;
        pf[ks] = *(const bf16x8*)&sP[r * 64 + ch];
      }
      bf16x8 vf[2][4];
      #pragma unroll
      for (int ks = 0; ks < 2; ++ks)
        #pragma unroll
        for (int nd = 0; nd < 4; ++nd) {
          int r = nd * 16 + l15;
          int ch = ((ks * 4 + l4) ^ (r & 7)) << 3;
          vf[ks][nd] = *(const bf16x8*)&sV[r * 64 + ch];
        }
      __builtin_amdgcn_s_setprio(1);
      #pragma unroll
      for (int ks = 0; ks < 2; ++ks)
        #pragma unroll
        for (int nd = 0; nd < 4; ++nd)
          cacc[nd] = __builtin_amdgcn_mfma_f32_16x16x32_bf16(pf[ks], vf[ks][nd], cacc[nd], 0, 0, 0);
      __builtin_amdgcn_s_setprio(0);
    }
    __syncthreads();   // all waves done reading sK/sV before next tile's staging
  }

  // epilogue: ctx / l, store natural layout (bf16)
  #pragma unroll
  for (int rr = 0; rr < 4; ++rr) {
    float rcp = 1.0f / lrun[rr];
    int qr = q0 + l4 * 4 + rr;
    #pragma unroll
    for (int nd = 0; nd < 4; ++nd) {
      float ov = cacc[nd][rr] * rcp;
      size_t ad = (size_t)(b * Sq + qr) * Dm + h * 64 + nd * 16 + l15;
      chi[ad] = (bf16)ov;
    }
  }
}

// ---------------- launch ----------------
extern "C" void kernel_launch(void* const* d_in, const int* in_sizes, int n_in,
                              void* d_out, int out_size, void* d_ws, size_t ws_size,
                              hipStream_t stream) {
  const float* x  = (const float*)d_in[0];
  const float* Wq = (const float*)d_in[1];
  const float* Wk = (const float*)d_in[2];
  const float* Wv = (const float*)d_in[3];
  const float* Wo = (const float*)d_in[4];
  const float* bo = (const float*)d_in[5];
  const float* W1 = (const float*)d_in[6];
  const float* b1 = (const float*)d_in[7];
  const float* W2 = (const float*)d_in[8];
  const float* b2 = (const float*)d_in[9];
  const float* g1 = (const float*)d_in[10];
  const float* s1 = (const float*)d_in[11];
  const float* g2 = (const float*)d_in[12];
  const float* s2 = (const float*)d_in[13];
  float* out = (float*)d_out;

  if (ws_size < 150994944ULL) return; // need 144 MB

  char* ws = (char*)d_ws;
  // weights (bf16, transposed)
  bf16* wqkvT_hi = (bf16*)(ws + 0);
  bf16* woT_hi   = (bf16*)(ws + 12582912);
  bf16* w1T_hi   = (bf16*)(ws + 16777216);
  bf16* w2T_hi   = (bf16*)(ws + 33554432);
  // region A (64 MB): h, q(hi/lo), k, vT  -> later a1
  char* rA = ws + 50331648;
  bf16* h_hi  = (bf16*)(rA + 0);
  bf16* q_hi  = (bf16*)(rA + 16777216); // q_lo at +AE, k at +2AE, vT at +4AE (EP0 offsets)
  bf16* q_lo  = (bf16*)(rA + 25165824);
  bf16* k_hi  = (bf16*)(rA + 33554432);
  bf16* vT_hi = (bf16*)(rA + 50331648);
  bf16* a1_hi = (bf16*)(rA + 0);        // 32 MB, reuses region A after attention
  // region B (16 MB): ctx -> later h2
  char* rB = ws + 117440512;
  bf16* ctx_hi = (bf16*)(rB + 0);
  bf16* h2_hi  = (bf16*)(rB + 0);       // LN2 overwrites ctx after Wo consumed it
  // region C (16 MB): x1 fp32
  float* x1 = (float*)(ws + 134217728);

  // 1) weight transforms (fused 4x 1024^2, then W1, W2)
  transpose_qkvo_kernel<<<dim3(16, 16, 4), 256, 0, stream>>>(Wq, Wk, Wv, Wo, wqkvT_hi, woT_hi);
  transpose_split_kernel<<<dim3(64, 16), 256, 0, stream>>>(W1, w1T_hi, 1024, 4096);
  transpose_split_kernel<<<dim3(16, 64), 256, 0, stream>>>(W2, w2T_hi, 4096, 1024);

  // 2) LN1
  ln_kernel<<<4096, 256, 0, stream>>>(x, g1, s1, h_hi);

  // 3) fused QKV GEMM (N = 3072)
  gemm_kernel<0><<<dim3(24, 64), 256, 0, stream>>>(h_hi, wqkvT_hi,
                                                   1024, 3072, q_hi, nullptr, nullptr, nullptr);
  // 4) attention (1024 LPT-ordered blocks, 6/CU capacity)
  attn_kernel<<<dim3(1024), 256, 0, stream>>>(q_hi, q_lo, k_hi, vT_hi, ctx_hi);

  // 5) Wo projection + bias + residual -> x1
  gemm_kernel<1><<<dim3(8, 64), 256, 0, stream>>>(ctx_hi, woT_hi,
                                                  1024, 1024, nullptr, x1, bo, x);
  // 6) LN2
  ln_kernel<<<4096, 256, 0, stream>>>(x1, g2, s2, h2_hi);

  // 7) FFN up + GELU -> a1
  gemm_kernel<2><<<dim3(32, 64), 256, 0, stream>>>(h2_hi, w1T_hi,
                                                   1024, 4096, a1_hi, nullptr, b1, nullptr);
  // 8) FFN down + bias + residual -> out
  gemm_kernel<1><<<dim3(8, 64), 256, 0, stream>>>(a1_hi, w2T_hi,
                                                  4096, 1024, nullptr, out, b2, x1);
}

// Round 8
// 402.779 us; speedup vs baseline: 1.3650x; 1.3650x over previous
//
#include <hip/hip_runtime.h>
#include <hip/hip_bf16.h>
#include <math.h>

typedef __bf16 bf16;
typedef __bf16 bf16x4 __attribute__((ext_vector_type(4)));
typedef __bf16 bf16x8 __attribute__((ext_vector_type(8)));
typedef float f32x4 __attribute__((ext_vector_type(4)));

#define DEV static __device__ __forceinline__

constexpr int Dm = 1024;   // model dim
constexpr int Sq = 2048;   // seq len
constexpr int Mrows = 4096; // B*S
constexpr size_t AE = (size_t)Mrows * Dm; // elems per activation array

DEV void gload_lds16(const void* g, void* l) {
  __builtin_amdgcn_global_load_lds((const __attribute__((address_space(1))) unsigned int*)g,
                                   (__attribute__((address_space(3))) unsigned int*)l,
                                   16, 0, 0);
}

DEV float gelu_f(float u) {
  const float c = 0.7978845608028654f; // sqrt(2/pi)
  float t = c * (u + 0.044715f * u * u * u);
  // 0.5*(1+tanh(t)) == sigmoid(2t)
  return u / (1.0f + __expf(-2.0f * t));
}

// ---------------- fused transpose of the four 1024x1024 weights ----------------
__global__ void transpose_qkvo_kernel(const float* __restrict__ Wq, const float* __restrict__ Wk,
                                      const float* __restrict__ Wv, const float* __restrict__ Wo,
                                      bf16* __restrict__ Tqkv, bf16* __restrict__ To) {
  const int z = blockIdx.z;
  const float* W = (z == 0) ? Wq : (z == 1) ? Wk : (z == 2) ? Wv : Wo;
  bf16* T = (z < 3) ? (Tqkv + (size_t)z * 1024 * 1024) : To;
  __shared__ float tile[64][65];
  const int t = threadIdx.x;
  const int nt = blockIdx.x * 64, kt = blockIdx.y * 64;
  #pragma unroll
  for (int i = 0; i < 16; ++i) {
    int id = i * 256 + t;
    int r = id >> 6, c = id & 63;
    tile[r][c] = W[(size_t)(kt + r) * 1024 + nt + c];
  }
  __syncthreads();
  #pragma unroll
  for (int i = 0; i < 16; ++i) {
    int id = i * 256 + t;
    int n = id >> 6, k = id & 63;
    T[(size_t)(nt + n) * 1024 + kt + k] = (bf16)tile[k][n];
  }
}

// ---------------- weight transpose: W[K][N] -> T[N][K] (bf16) ----------------
__global__ void transpose_split_kernel(const float* __restrict__ W,
                                       bf16* __restrict__ Thi,
                                       int K, int N) {
  __shared__ float tile[64][65];
  const int t = threadIdx.x;
  const int nt = blockIdx.x * 64, kt = blockIdx.y * 64;
  #pragma unroll
  for (int i = 0; i < 16; ++i) {
    int id = i * 256 + t;
    int r = id >> 6, c = id & 63;
    tile[r][c] = W[(size_t)(kt + r) * N + nt + c];
  }
  __syncthreads();
  #pragma unroll
  for (int i = 0; i < 16; ++i) {
    int id = i * 256 + t;
    int n = id >> 6, k = id & 63;
    Thi[(size_t)(nt + n) * K + kt + k] = (bf16)tile[k][n];
  }
}

// ---------------- LayerNorm -> bf16 (one block per row of 1024) ----------------
__global__ void ln_kernel(const float* __restrict__ x,
                          const float* __restrict__ gamma, const float* __restrict__ beta,
                          bf16* __restrict__ ohi) {
  const int row = blockIdx.x, t = threadIdx.x;
  const float4 v = ((const float4*)(x + (size_t)row * Dm))[t];
  float s = v.x + v.y + v.z + v.w;
  float sq = v.x * v.x + v.y * v.y + v.z * v.z + v.w * v.w;
  #pragma unroll
  for (int off = 1; off < 64; off <<= 1) {
    s += __shfl_xor(s, off);
    sq += __shfl_xor(sq, off);
  }
  __shared__ float red[8];
  const int wave = t >> 6, lane = t & 63;
  if (lane == 0) { red[wave] = s; red[4 + wave] = sq; }
  __syncthreads();
  s = red[0] + red[1] + red[2] + red[3];
  sq = red[4] + red[5] + red[6] + red[7];
  const float mean = s * (1.0f / 1024.0f);
  const float var = sq * (1.0f / 1024.0f) - mean * mean;
  const float inv = 1.0f / sqrtf(var + 1e-5f);
  const float4 g4 = ((const float4*)gamma)[t];
  const float4 b4 = ((const float4*)beta)[t];
  bf16x4 hv;
  hv[0] = (bf16)((v.x - mean) * inv * g4.x + b4.x);
  hv[1] = (bf16)((v.y - mean) * inv * g4.y + b4.y);
  hv[2] = (bf16)((v.z - mean) * inv * g4.z + b4.z);
  hv[3] = (bf16)((v.w - mean) * inv * g4.w + b4.w);
  ((bf16x4*)(ohi + (size_t)row * Dm))[t] = hv;
}

// ---------------- bf16 GEMM: C = A @ B^T(stored [N][K]) ----------------
// kt-outer, single pass. Tile 64x128, 4 waves (2x2), 24KB LDS -> 6 blocks/CU.
// XCD-swizzled block ids. EP: 0 = QKV epilogue, 1 = bias+residual fp32, 2 = gelu.
template<int EP>
__global__ __launch_bounds__(256, 6) void gemm_kernel(
    const bf16* __restrict__ Ahi,
    const bf16* __restrict__ Bthi,
    int K, int N,
    bf16* __restrict__ Ohi,
    float* __restrict__ Of,
    const float* __restrict__ bias, const float* __restrict__ resid) {
  const int t = threadIdx.x, wave = t >> 6, lane = t & 63;
  const int wr = wave >> 1, wc = wave & 1;
  const int l15 = lane & 15, l4 = lane >> 4;
  // bijective XCD swizzle (nwg % 8 == 0 for all launches)
  const int nwg = gridDim.x * gridDim.y;
  const int p0 = blockIdx.y * gridDim.x + blockIdx.x;
  const int swz = (p0 & 7) * (nwg >> 3) + (p0 >> 3);
  const int row0 = (swz / gridDim.x) * 64, col0 = (swz % gridDim.x) * 128;

  __shared__ __align__(16) bf16 sAh[64 * 64];
  __shared__ __align__(16) bf16 sBh[128 * 64];

  f32x4 acc[2][4];
  #pragma unroll
  for (int m = 0; m < 2; ++m)
    #pragma unroll
    for (int n = 0; n < 4; ++n)
      acc[m][n] = (f32x4){0.f, 0.f, 0.f, 0.f};

  for (int kt = 0; kt < K; kt += 64) {
    // stage A [64][64] and B [128][64]; global chunk pre-swizzled, LDS linear
    #pragma unroll
    for (int p = 0; p < 2; ++p) {
      int id = p * 256 + t;
      int r = id >> 3, c = id & 7;
      int cs = (c ^ (r & 7)) << 3;
      gload_lds16(Ahi + (size_t)(row0 + r) * K + kt + cs,
                  (char*)sAh + (p * 256 + wave * 64) * 16);
    }
    #pragma unroll
    for (int p = 0; p < 4; ++p) {
      int id = p * 256 + t;
      int r = id >> 3, c = id & 7;
      int cs = (c ^ (r & 7)) << 3;
      gload_lds16(Bthi + (size_t)(col0 + r) * K + kt + cs,
                  (char*)sBh + (p * 256 + wave * 64) * 16);
    }
    __syncthreads();

    bf16x8 afh[2][2], bfh[4][2];
    #pragma unroll
    for (int m = 0; m < 2; ++m)
      #pragma unroll
      for (int ks = 0; ks < 2; ++ks) {
        int r = wr * 32 + m * 16 + l15;
        int ch = ((ks * 4 + l4) ^ (r & 7)) << 3;
        afh[m][ks] = *(const bf16x8*)&sAh[r * 64 + ch];
      }
    #pragma unroll
    for (int n = 0; n < 4; ++n)
      #pragma unroll
      for (int ks = 0; ks < 2; ++ks) {
        int r = wc * 64 + n * 16 + l15;
        int ch = ((ks * 4 + l4) ^ (r & 7)) << 3;
        bfh[n][ks] = *(const bf16x8*)&sBh[r * 64 + ch];
      }
    #pragma unroll
    for (int ks = 0; ks < 2; ++ks)
      #pragma unroll
      for (int m = 0; m < 2; ++m)
        #pragma unroll
        for (int n = 0; n < 4; ++n)
          acc[m][n] = __builtin_amdgcn_mfma_f32_16x16x32_bf16(afh[m][ks], bfh[n][ks], acc[m][n], 0, 0, 0);
    __syncthreads();
  }

  // epilogue
  #pragma unroll
  for (int m = 0; m < 2; ++m)
    #pragma unroll
    for (int n = 0; n < 4; ++n)
      #pragma unroll
      for (int rr = 0; rr < 4; ++rr) {
        int row = row0 + wr * 32 + m * 16 + l4 * 4 + rr;
        int col = col0 + wc * 64 + n * 16 + l15;
        float v = acc[m][n][rr];
        if constexpr (EP == 0) {
          int which = col >> 10;
          int c = col & 1023;
          if (which == 0) {
            float q = v * 0.18033688011111793f;  // 0.125 * log2(e) pre-folded into Q
            bf16 hi = (bf16)q;
            size_t ad = (size_t)row * Dm + c;
            Ohi[ad] = hi; Ohi[AE + ad] = (bf16)(q - (float)hi);  // q hi/lo
          } else if (which == 1) {
            size_t ad = (size_t)row * Dm + c;
            Ohi[2 * AE + ad] = (bf16)v;                          // k
          } else {
            size_t ad = ((size_t)(row >> 11) * Dm + c) * Sq + (row & (Sq - 1));
            Ohi[4 * AE + ad] = (bf16)v;                          // v transposed [b][h*64+hd][s]
          }
        } else if constexpr (EP == 1) {
          size_t ad = (size_t)row * N + col;
          Of[ad] = v + bias[col] + resid[ad];
        } else {
          size_t ad = (size_t)row * N + col;
          Ohi[ad] = (bf16)gelu_f(v + bias[col]);
        }
      }
}

// ---------------- causal flash attention, single-buffered K/V ----------------
// grid: 1024 blocks, one 64-row q-tile each; 4 waves x 16 q-rows.
// LPT schedule: heaviest q-tiles dispatched first (qt = 31 - qidx), tail backfills with
// cost-1 blocks under ANY dispatcher. i&7 spreads XCDs; 4 heads per XCD keep K/V L2-resident.
// launch_bounds min-occupancy 4 (VGPR cap 128 -> NO SPILL; r7's (256,6) capped VGPR at 40
// and spilled 230MB/dispatch to scratch). Actual occupancy is LDS-limited: 24KB -> 6/CU.
__global__ __launch_bounds__(256, 4) void attn_kernel(
    const bf16* __restrict__ qhi, const bf16* __restrict__ qlo,
    const bf16* __restrict__ khi, const bf16* __restrict__ vthi,
    bf16* __restrict__ chi) {
  const int t = threadIdx.x, wave = t >> 6, lane = t & 63;
  const int l15 = lane & 15, l4 = lane >> 4;
  const int i = blockIdx.x;
  const int xcd = i & 7, j = i >> 3;   // j in [0,128) within XCD
  const int hl = j & 3, qidx = j >> 2; // 4 heads/XCD, qidx in [0,32)
  const int qt = 31 - qidx;            // descending cost (LPT)
  const int bh = xcd * 4 + hl;
  const int b = bh >> 4, h = bh & 15;
  const int qb = qt * 64;
  const int q0 = qb + wave * 16;

  __shared__ __align__(16) bf16 sK[4096], sV[4096], sP[4096];  // 24 KB

  // hoist Q fragments (hi and lo); Q is pre-scaled by 0.125*log2e
  bf16x8 qfh[2], qfl[2];
  #pragma unroll
  for (int ks = 0; ks < 2; ++ks) {
    size_t ad = (size_t)(b * Sq + q0 + l15) * Dm + h * 64 + ks * 32 + l4 * 8;
    qfh[ks] = *(const bf16x8*)&qhi[ad];
    qfl[ks] = *(const bf16x8*)&qlo[ad];
  }

  f32x4 cacc[4];
  float mrun[4], lrun[4];
  #pragma unroll
  for (int nd = 0; nd < 4; ++nd) cacc[nd] = (f32x4){0.f, 0.f, 0.f, 0.f};
  #pragma unroll
  for (int rr = 0; rr < 4; ++rr) { mrun[rr] = -3e38f; lrun[rr] = 0.f; }

  for (int kb = 0; kb <= qb; kb += 64) {
    // stage K [64 s][64 d] and V^T [64 d][64 s] (single buffer; cross-block TLP hides drain)
    #pragma unroll
    for (int p = 0; p < 2; ++p) {
      int id = p * 256 + t;
      int r = id >> 3, c = id & 7;
      int cc = (c ^ (r & 7)) << 3;
      size_t ka = (size_t)(b * Sq + kb + r) * Dm + h * 64 + cc;
      size_t va = (size_t)(b * Dm + h * 64 + r) * Sq + kb + cc;
      gload_lds16(&khi[ka], (char*)sK + (p * 256 + wave * 64) * 16);
      gload_lds16(&vthi[va], (char*)sV + (p * 256 + wave * 64) * 16);
    }
    __syncthreads();   // drains vmcnt (gload_lds) for all waves

    // ---------- S = Q K^T (q_hi + q_lo passes) ----------
    f32x4 sacc[4];
    #pragma unroll
    for (int nk = 0; nk < 4; ++nk) sacc[nk] = (f32x4){0.f, 0.f, 0.f, 0.f};
    {
      bf16x8 kf[4][2];
      #pragma unroll
      for (int nk = 0; nk < 4; ++nk)
        #pragma unroll
        for (int ks = 0; ks < 2; ++ks) {
          int r = nk * 16 + l15;
          int ch = ((ks * 4 + l4) ^ (r & 7)) << 3;
          kf[nk][ks] = *(const bf16x8*)&sK[r * 64 + ch];
        }
      __builtin_amdgcn_s_setprio(1);
      #pragma unroll
      for (int ks = 0; ks < 2; ++ks)
        #pragma unroll
        for (int nk = 0; nk < 4; ++nk)
          sacc[nk] = __builtin_amdgcn_mfma_f32_16x16x32_bf16(qfh[ks], kf[nk][ks], sacc[nk], 0, 0, 0);
      #pragma unroll
      for (int ks = 0; ks < 2; ++ks)
        #pragma unroll
        for (int nk = 0; nk < 4; ++nk)
          sacc[nk] = __builtin_amdgcn_mfma_f32_16x16x32_bf16(qfl[ks], kf[nk][ks], sacc[nk], 0, 0, 0);
      __builtin_amdgcn_s_setprio(0);
    }

    // ---------- causal mask (diagonal block only), online softmax in log2 domain ----------
    const bool diag = (kb == qb);
    #pragma unroll
    for (int rr = 0; rr < 4; ++rr) {
      float mx = -3e38f;
      #pragma unroll
      for (int nk = 0; nk < 4; ++nk) {
        float tv = sacc[nk][rr];
        if (diag && (nk * 16 + l15 > wave * 16 + l4 * 4 + rr)) tv = -3e38f;
        sacc[nk][rr] = tv;
        mx = fmaxf(mx, tv);
      }
      mx = fmaxf(mx, __shfl_xor(mx, 1));
      mx = fmaxf(mx, __shfl_xor(mx, 2));
      mx = fmaxf(mx, __shfl_xor(mx, 4));
      mx = fmaxf(mx, __shfl_xor(mx, 8));
      float mold = mrun[rr];
      if (mx > mold + 8.0f) {        // defer-max: only rescale on big jumps
        float corr = exp2f(mold - mx);
        lrun[rr] *= corr;
        #pragma unroll
        for (int nd = 0; nd < 4; ++nd) cacc[nd][rr] *= corr;
        mrun[rr] = mx;
        mold = mx;
      }
      float rs = 0.f;
      #pragma unroll
      for (int nk = 0; nk < 4; ++nk) {
        float p = exp2f(sacc[nk][rr] - mold);
        sacc[nk][rr] = p;
        rs += p;
      }
      rs += __shfl_xor(rs, 1);
      rs += __shfl_xor(rs, 2);
      rs += __shfl_xor(rs, 4);
      rs += __shfl_xor(rs, 8);
      lrun[rr] += rs;
    }

    // ---------- write P (bf16) to swizzled LDS (wave-private rows; no barrier needed) ----------
    #pragma unroll
    for (int nk = 0; nk < 4; ++nk)
      #pragma unroll
      for (int rr = 0; rr < 4; ++rr) {
        int row = wave * 16 + l4 * 4 + rr;
        int col = nk * 16 + l15;
        int ad = row * 64 + (((col >> 3) ^ (row & 7)) << 3) + (col & 7);
        sP[ad] = (bf16)sacc[nk][rr];
      }

    // ---------- ctx += P V ----------
    {
      bf16x8 pf[2];
      #pragma unroll
      for (int ks = 0; ks < 2; ++ks) {
        int r = wave * 16 + l15;
        int ch = ((ks * 4 + l4) ^ (r & 7)) << 3;
        pf[ks] = *(const bf16x8*)&sP[r * 64 + ch];
      }
      bf16x8 vf[2][4];
      #pragma unroll
      for (int ks = 0; ks < 2; ++ks)
        #pragma unroll
        for (int nd = 0; nd < 4; ++nd) {
          int r = nd * 16 + l15;
          int ch = ((ks * 4 + l4) ^ (r & 7)) << 3;
          vf[ks][nd] = *(const bf16x8*)&sV[r * 64 + ch];
        }
      __builtin_amdgcn_s_setprio(1);
      #pragma unroll
      for (int ks = 0; ks < 2; ++ks)
        #pragma unroll
        for (int nd = 0; nd < 4; ++nd)
          cacc[nd] = __builtin_amdgcn_mfma_f32_16x16x32_bf16(pf[ks], vf[ks][nd], cacc[nd], 0, 0, 0);
      __builtin_amdgcn_s_setprio(0);
    }
    __syncthreads();   // all waves done reading sK/sV before next tile's staging
  }

  // epilogue: ctx / l, store natural layout (bf16)
  #pragma unroll
  for (int rr = 0; rr < 4; ++rr) {
    float rcp = 1.0f / lrun[rr];
    int qr = q0 + l4 * 4 + rr;
    #pragma unroll
    for (int nd = 0; nd < 4; ++nd) {
      float ov = cacc[nd][rr] * rcp;
      size_t ad = (size_t)(b * Sq + qr) * Dm + h * 64 + nd * 16 + l15;
      chi[ad] = (bf16)ov;
    }
  }
}

// ---------------- launch ----------------
extern "C" void kernel_launch(void* const* d_in, const int* in_sizes, int n_in,
                              void* d_out, int out_size, void* d_ws, size_t ws_size,
                              hipStream_t stream) {
  const float* x  = (const float*)d_in[0];
  const float* Wq = (const float*)d_in[1];
  const float* Wk = (const float*)d_in[2];
  const float* Wv = (const float*)d_in[3];
  const float* Wo = (const float*)d_in[4];
  const float* bo = (const float*)d_in[5];
  const float* W1 = (const float*)d_in[6];
  const float* b1 = (const float*)d_in[7];
  const float* W2 = (const float*)d_in[8];
  const float* b2 = (const float*)d_in[9];
  const float* g1 = (const float*)d_in[10];
  const float* s1 = (const float*)d_in[11];
  const float* g2 = (const float*)d_in[12];
  const float* s2 = (const float*)d_in[13];
  float* out = (float*)d_out;

  if (ws_size < 150994944ULL) return; // need 144 MB

  char* ws = (char*)d_ws;
  // weights (bf16, transposed)
  bf16* wqkvT_hi = (bf16*)(ws + 0);
  bf16* woT_hi   = (bf16*)(ws + 12582912);
  bf16* w1T_hi   = (bf16*)(ws + 16777216);
  bf16* w2T_hi   = (bf16*)(ws + 33554432);
  // region A (64 MB): h, q(hi/lo), k, vT  -> later a1
  char* rA = ws + 50331648;
  bf16* h_hi  = (bf16*)(rA + 0);
  bf16* q_hi  = (bf16*)(rA + 16777216); // q_lo at +AE, k at +2AE, vT at +4AE (EP0 offsets)
  bf16* q_lo  = (bf16*)(rA + 25165824);
  bf16* k_hi  = (bf16*)(rA + 33554432);
  bf16* vT_hi = (bf16*)(rA + 50331648);
  bf16* a1_hi = (bf16*)(rA + 0);        // 32 MB, reuses region A after attention
  // region B (16 MB): ctx -> later h2
  char* rB = ws + 117440512;
  bf16* ctx_hi = (bf16*)(rB + 0);
  bf16* h2_hi  = (bf16*)(rB + 0);       // LN2 overwrites ctx after Wo consumed it
  // region C (16 MB): x1 fp32
  float* x1 = (float*)(ws + 134217728);

  // 1) weight transforms (fused 4x 1024^2, then W1, W2)
  transpose_qkvo_kernel<<<dim3(16, 16, 4), 256, 0, stream>>>(Wq, Wk, Wv, Wo, wqkvT_hi, woT_hi);
  transpose_split_kernel<<<dim3(64, 16), 256, 0, stream>>>(W1, w1T_hi, 1024, 4096);
  transpose_split_kernel<<<dim3(16, 64), 256, 0, stream>>>(W2, w2T_hi, 4096, 1024);

  // 2) LN1
  ln_kernel<<<4096, 256, 0, stream>>>(x, g1, s1, h_hi);

  // 3) fused QKV GEMM (N = 3072)
  gemm_kernel<0><<<dim3(24, 64), 256, 0, stream>>>(h_hi, wqkvT_hi,
                                                   1024, 3072, q_hi, nullptr, nullptr, nullptr);
  // 4) attention (1024 LPT-ordered blocks, 6/CU via LDS limit, no VGPR spill)
  attn_kernel<<<dim3(1024), 256, 0, stream>>>(q_hi, q_lo, k_hi, vT_hi, ctx_hi);

  // 5) Wo projection + bias + residual -> x1
  gemm_kernel<1><<<dim3(8, 64), 256, 0, stream>>>(ctx_hi, woT_hi,
                                                  1024, 1024, nullptr, x1, bo, x);
  // 6) LN2
  ln_kernel<<<4096, 256, 0, stream>>>(x1, g2, s2, h2_hi);

  // 7) FFN up + GELU -> a1
  gemm_kernel<2><<<dim3(32, 64), 256, 0, stream>>>(h2_hi, w1T_hi,
                                                   1024, 4096, a1_hi, nullptr, b1, nullptr);
  // 8) FFN down + bias + residual -> out
  gemm_kernel<1><<<dim3(8, 64), 256, 0, stream>>>(a1_hi, w2T_hi,
                                                  4096, 1024, nullptr, out, b2, x1);
}